// Round 13
// baseline (259.019 us; speedup 1.0000x reference)
//
#include <hip/hip_runtime.h>
#include <math.h>

#define EMBED 384
#define HID 64
#define NE 4
#define TPB 512               // 8 waves
#define NW 8                  // waves per block
#define DSL 48                // d-slice per wave (8*48 = 384)
#define TOKB 256              // tokens per block -> grid 512, 2 blocks/CU
#define CHUNK 64              // stats chunk
#define BATCH 16              // compute/reduce pipeline batch

__global__ __launch_bounds__(TPB) void router_main(
    const float* __restrict__ x, const float* __restrict__ lnw,
    const float* __restrict__ lnb, const float* __restrict__ w1,
    const float* __restrict__ w2, float* __restrict__ out,
    float* __restrict__ ws, int ntok)
{
  __shared__ float partial[BATCH][NW][HID];   // 32 KB
  __shared__ float stats[CHUNK][2];           // mu, rstd per chunk token
  __shared__ float cpart[2][NW][HID];         // c1/c2 cross-wave reduce
  __shared__ float red[2 * NE];               // block aux combine

  const int tid  = (int)threadIdx.x;
  const int lane = tid & 63;
  const int wvu  = __builtin_amdgcn_readfirstlane(tid >> 6);  // uniform wave id
  const int dbase = wvu * DSL;

  // ---- prologue: wave's wln slice into registers (lane = j column) ----
  // wln[d][j] = lnw[d] * w1[d][j]; also per-lane c1[j], c2[j] partials.
  float wreg[DSL];
  {
    float c1p = 0.f, c2p = 0.f;
    #pragma unroll
    for (int k = 0; k < DSL; ++k) {
      const float wv1 = w1[(size_t)(dbase + k) * HID + lane];  // coalesced
      const float sw  = lnw[dbase + k];                        // uniform -> s_load
      const float sb  = lnb[dbase + k];                        // uniform -> s_load
      wreg[k] = wv1 * sw;
      c1p += wreg[k];
      c2p = fmaf(sb, wv1, c2p);
    }
    cpart[0][wvu][lane] = c1p;
    cpart[1][wvu][lane] = c2p;
  }
  if (tid < 2 * NE) red[tid] = 0.f;
  __syncthreads();

  float c1 = 0.f, c2 = 0.f;
  #pragma unroll
  for (int w = 0; w < NW; ++w) {
    c1 += cpart[0][w][lane];
    c2 += cpart[1][w][lane];
  }
  const float4 w2r = reinterpret_cast<const float4*>(w2)[lane];  // w2[j][0..3]

  const int blk0 = (int)blockIdx.x * TOKB;
  // uniform scalar-load base for this wave's d-slice
  const float* __restrict__ xw = x + (size_t)blk0 * EMBED + dbase;

  // per-wave aux accumulators (meaningful on lane 0 only)
  float ps0 = 0.f, ps1 = 0.f, ps2 = 0.f, ps3 = 0.f;
  float pc0 = 0.f, pc1 = 0.f, pc2 = 0.f, pc3 = 0.f;

  for (int c0 = 0; c0 < TOKB; c0 += CHUNK) {
    // ---- phase A: LN stats for tokens [c0, c0+CHUNK), 8 lanes per token ----
    {
      const int t    = tid >> 3;          // 0..63 chunk-local token
      const int part = tid & 7;           // d-part
      const float* xr = x + (size_t)(blk0 + c0 + t) * EMBED + part * (EMBED / 8);
      float s = 0.f, s2 = 0.f;
      #pragma unroll
      for (int k = 0; k < (EMBED / 8) / 4; ++k) {
        float4 v = reinterpret_cast<const float4*>(xr)[k];
        s += (v.x + v.y) + (v.z + v.w);
        s2 = fmaf(v.x, v.x, s2);
        s2 = fmaf(v.y, v.y, s2);
        s2 = fmaf(v.z, v.z, s2);
        s2 = fmaf(v.w, v.w, s2);
      }
      s  += __shfl_xor(s, 1);  s  += __shfl_xor(s, 2);  s  += __shfl_xor(s, 4);
      s2 += __shfl_xor(s2, 1); s2 += __shfl_xor(s2, 2); s2 += __shfl_xor(s2, 4);
      if (part == 0) {
        const float mu  = s * (1.f / EMBED);
        const float var = fmaf(-mu, mu, s2 * (1.f / EMBED));
        stats[t][0] = mu;
        stats[t][1] = rsqrtf(var + 1e-5f);
      }
    }
    __syncthreads();

    // ---- phase B: batches of 16 tokens {compute partials, barrier, reduce} ----
    for (int b0 = 0; b0 < CHUNK; b0 += BATCH) {
      #pragma unroll 1
      for (int bt = 0; bt < BATCH; ++bt) {
        const int t = c0 + b0 + bt;                   // block-local token
        const float* __restrict__ p = xw + (size_t)t * EMBED;  // uniform -> s_load
        float pacc = 0.f;
        #pragma unroll
        for (int k = 0; k < DSL; ++k)
          pacc = fmaf(p[k], wreg[k], pacc);           // v_fmac(s, v, v)
        partial[bt][wvu][lane] = pacc;
      }
      __syncthreads();

      // each wave reduces 2 tokens: bt = wvu, wvu+8
      #pragma unroll
      for (int r = 0; r < 2; ++r) {
        const int bt = wvu + r * NW;
        const int tl = c0 + b0 + bt;                  // block-local token
        float h = 0.f;
        #pragma unroll
        for (int w = 0; w < NW; ++w) h += partial[bt][w][lane];
        const float mu = stats[b0 + bt][0];
        const float rs = stats[b0 + bt][1];
        const float hid = fmaf(rs, fmaf(-mu, c1, h), c2);
        const float g = 0.5f * hid * (1.f + erff(hid * 0.7071067811865475f));
        float l0 = g * w2r.x, l1 = g * w2r.y, l2 = g * w2r.z, l3 = g * w2r.w;
        #pragma unroll
        for (int off = 1; off < 64; off <<= 1) {
          l0 += __shfl_xor(l0, off);
          l1 += __shfl_xor(l1, off);
          l2 += __shfl_xor(l2, off);
          l3 += __shfl_xor(l3, off);
        }
        if (lane == 0) {
          l0 *= 0.5f; l1 *= 0.5f; l2 *= 0.5f; l3 *= 0.5f;   // /T, T=2
          const float mx = fmaxf(fmaxf(l0, l1), fmaxf(l2, l3));
          const float e0 = expf(l0 - mx), e1 = expf(l1 - mx),
                      e2 = expf(l2 - mx), e3 = expf(l3 - mx);
          const float inv = 1.f / (e0 + e1 + e2 + e3);
          const float p0 = e0 * inv, p1 = e1 * inv,
                      p2 = e2 * inv, p3 = e3 * inv;
          int best = 0; float bp = p0;
          if (p1 > bp) { bp = p1; best = 1; }
          if (p2 > bp) { bp = p2; best = 2; }
          if (p3 > bp) { bp = p3; best = 3; }
          const int tok = blk0 + tl;
          if (tok < ntok) {
            *reinterpret_cast<float4*>(out + (size_t)tok * 4) =
                make_float4(p0, p1, p2, p3);
            out[(size_t)ntok * 4 + tok] = (float)best;
            float* o3 = out + (size_t)ntok * 5 + 1 + (size_t)tok * 4;
            o3[0] = p0; o3[1] = p1; o3[2] = p2; o3[3] = p3;
            ps0 += p0; ps1 += p1; ps2 += p2; ps3 += p3;
            pc0 += (best == 0) ? 1.f : 0.f;
            pc1 += (best == 1) ? 1.f : 0.f;
            pc2 += (best == 2) ? 1.f : 0.f;
            pc3 += (best == 3) ? 1.f : 0.f;
          }
        }
      }
      __syncthreads();
    }
  }

  // ---- aux: per-wave lane0 -> LDS -> 8 global atomics per block ----
  if (lane == 0) {
    atomicAdd(&red[0], ps0); atomicAdd(&red[1], ps1);
    atomicAdd(&red[2], ps2); atomicAdd(&red[3], ps3);
    atomicAdd(&red[NE + 0], pc0); atomicAdd(&red[NE + 1], pc1);
    atomicAdd(&red[NE + 2], pc2); atomicAdd(&red[NE + 3], pc3);
  }
  __syncthreads();
  if (tid < 2 * NE) atomicAdd(&ws[tid], red[tid]);
}

__global__ void router_finalize(const float* __restrict__ ws,
                                float* __restrict__ out, int ntok)
{
  if (threadIdx.x == 0 && blockIdx.x == 0) {
    const float invN = 1.f / (float)ntok;
    float aux = 0.f;
    #pragma unroll
    for (int e = 0; e < NE; ++e)
      aux = fmaf(ws[NE + e] * invN, ws[e] * invN, aux);
    out[(size_t)ntok * 5] = (float)NE * aux;
  }
}

extern "C" void kernel_launch(void* const* d_in, const int* in_sizes, int n_in,
                              void* d_out, int out_size, void* d_ws, size_t ws_size,
                              hipStream_t stream) {
  const float* x   = (const float*)d_in[0];
  const float* lnw = (const float*)d_in[1];
  const float* lnb = (const float*)d_in[2];
  const float* w1  = (const float*)d_in[3];
  const float* w2  = (const float*)d_in[4];
  float* out = (float*)d_out;
  float* ws  = (float*)d_ws;

  const int ntok = in_sizes[0] / EMBED;   // 131072

  hipMemsetAsync(d_ws, 0, 2 * NE * sizeof(float), stream);

  const int blocks = (ntok + TOKB - 1) / TOKB;   // 512
  router_main<<<blocks, TPB, 0, stream>>>(x, lnw, lnb, w1, w2, out, ws, ntok);
  router_finalize<<<1, 64, 0, stream>>>(ws, out, ntok);
}